// Round 2
// baseline (190.277 us; speedup 1.0000x reference)
//
#include <hip/hip_runtime.h>

// SSA forward, f32 I/O:
//   q = heads(lif(bn(x Wq^T))), k = heads(lif(bn(x Wk^T))), v = heads(bn(x Wv^T))
//   o = 0.125 * q @ (k^T v)   (no softmax -> associativity), out = bn(o Wp^T)
// Q/K pre-LIF GEMMs use 3-segment bf16 split (K=1536) for ~f32 accuracy
// (spike threshold is precision-critical); v/o/proj paths are plain bf16 MFMA.

#define T_ 4
#define B_ 4
#define N_ 1024
#define C_ 512
#define H_ 8
#define M_ (T_*B_*N_)   // 16384

typedef __bf16 bf16x8 __attribute__((ext_vector_type(8)));
typedef float  floatx4 __attribute__((ext_vector_type(4)));

__device__ __forceinline__ float bf2f(unsigned short u) {
  union { unsigned int i; float f; } v; v.i = ((unsigned int)u) << 16; return v.f;
}
__device__ __forceinline__ unsigned short f2bf(float f) {
  unsigned int x = __float_as_uint(f);
  return (unsigned short)((x + 0x7fffu + ((x >> 16) & 1u)) >> 16);  // RNE
}

// ---------------------------------------------------------------------------
// f32 -> 3-segment bf16 split. mode 0 (activations): [hi | lo | hi]
//                              mode 1 (weights):     [hi | hi | lo]
// Paired contraction gives xh*wh + xl*wh + xh*wl  (residual xl*wl ~ 2^-18).
// ---------------------------------------------------------------------------
__global__ __launch_bounds__(256) void prep_split(const float* __restrict__ src,
                                                  unsigned short* __restrict__ dst,
                                                  int nelem, int mode) {
  const int idx = (blockIdx.x * 256 + threadIdx.x) * 4;
  if (idx >= nelem) return;
  const float4 v = *(const float4*)(src + idx);
  const int row = idx >> 9, k = idx & 511;
  const size_t base = (size_t)row * 1536 + k;
  ushort4 hi, lo;
  float vv[4] = {v.x, v.y, v.z, v.w};
  unsigned short h[4], l[4];
#pragma unroll
  for (int j = 0; j < 4; ++j) {
    h[j] = f2bf(vv[j]);
    l[j] = f2bf(vv[j] - bf2f(h[j]));
  }
  hi = ushort4{h[0], h[1], h[2], h[3]};
  lo = ushort4{l[0], l[1], l[2], l[3]};
  *(ushort4*)(dst + base) = hi;
  *(ushort4*)(dst + base + 512)  = (mode == 0) ? lo : hi;
  *(ushort4*)(dst + base + 1024) = (mode == 0) ? hi : lo;
}

// plain f32 -> bf16 cast (v / proj weights)
__global__ __launch_bounds__(256) void prep_cast(const float* __restrict__ src,
                                                 unsigned short* __restrict__ dst,
                                                 int nelem) {
  const int idx = (blockIdx.x * 256 + threadIdx.x) * 4;
  if (idx >= nelem) return;
  const float4 v = *(const float4*)(src + idx);
  ushort4 o{f2bf(v.x), f2bf(v.y), f2bf(v.z), f2bf(v.w)};
  *(ushort4*)(dst + idx) = o;
}

struct GemmJob {
  const unsigned short* w;   // bf16 [512][ldb]
  int ldb, K;
  const float* bias; const float* gam; const float* bet; const float* mu; const float* var;
  float* out32;              // f32 out (pre-LIF precision / final output)
  unsigned short* out16;     // bf16 out
};
struct GemmJobs { GemmJob j[3]; };

// ---------------------------------------------------------------------------
// y[m,n] = sum_k A[m,k] W[n,k] (+ BN epilogue). 128x128 tile, BK=32, 4 waves,
// 16x16x32 bf16 MFMA, global_load_lds width-16. Flat grid with XCD-chunked
// swizzle so the (njobs*4) blocks sharing an A m-panel land on one XCD.
// ---------------------------------------------------------------------------
__global__ __launch_bounds__(256, 2) void gemm_bn(const unsigned short* __restrict__ A,
                                                  int lda, GemmJobs jobs, int njobs) {
  const int total = gridDim.x;
  const int logical = (blockIdx.x & 7) * (total >> 3) + (blockIdx.x >> 3);
  const int per_panel = njobs * 4;
  const int panel = logical / per_panel;
  const int rem = logical - panel * per_panel;
  const GemmJob job = jobs.j[rem >> 2];
  const int m0 = panel * 128;
  const int n0 = (rem & 3) * 128;

  const int tid = threadIdx.x;
  const int wv = tid >> 6;
  const int lane = tid & 63;

  __shared__ unsigned short As[128 * 32];
  __shared__ unsigned short Bs[128 * 32];

  floatx4 acc[4][4];
#pragma unroll
  for (int i = 0; i < 4; ++i)
#pragma unroll
    for (int j = 0; j < 4; ++j) acc[i][j] = floatx4{0.f, 0.f, 0.f, 0.f};

  const int wr = wv >> 1, wc = wv & 1;
  const int arow = wr * 64 + (lane & 15);
  const int brow = wc * 64 + (lane & 15);
  const int koff = (lane >> 4) * 8;
  const int srow = lane >> 2;
  const int scol = (lane & 3) * 8;

  for (int k0 = 0; k0 < job.K; k0 += 32) {
#pragma unroll
    for (int q = 0; q < 2; ++q) {
      const int chunk = wv * 2 + q;
      const unsigned short* ga = A + (size_t)(m0 + chunk * 16 + srow) * lda + k0 + scol;
      __builtin_amdgcn_global_load_lds((__attribute__((address_space(1))) void*)ga,
                                       (__attribute__((address_space(3))) void*)(As + chunk * 512),
                                       16, 0, 0);
      const unsigned short* gb = job.w + (size_t)(n0 + chunk * 16 + srow) * job.ldb + k0 + scol;
      __builtin_amdgcn_global_load_lds((__attribute__((address_space(1))) void*)gb,
                                       (__attribute__((address_space(3))) void*)(Bs + chunk * 512),
                                       16, 0, 0);
    }
    __syncthreads();
    bf16x8 a[4], b[4];
#pragma unroll
    for (int i = 0; i < 4; ++i)
      a[i] = *(const bf16x8*)(As + (arow + 16 * i) * 32 + koff);
#pragma unroll
    for (int j = 0; j < 4; ++j)
      b[j] = *(const bf16x8*)(Bs + (brow + 16 * j) * 32 + koff);
#pragma unroll
    for (int i = 0; i < 4; ++i)
#pragma unroll
      for (int j = 0; j < 4; ++j)
        acc[i][j] = __builtin_amdgcn_mfma_f32_16x16x32_bf16(a[i], b[j], acc[i][j], 0, 0, 0);
    __syncthreads();
  }

  float scl[4], sft[4];
#pragma unroll
  for (int j = 0; j < 4; ++j) {
    const int c = n0 + wc * 64 + j * 16 + (lane & 15);
    const float s = job.gam[c] * rsqrtf(job.var[c] + 1e-5f);
    scl[j] = s;
    sft[j] = (job.bias[c] - job.mu[c]) * s + job.bet[c];
  }
  const int rbase = m0 + wr * 64 + (lane >> 4) * 4;
#pragma unroll
  for (int i = 0; i < 4; ++i) {
#pragma unroll
    for (int r = 0; r < 4; ++r) {
      const size_t mrow = (size_t)(rbase + 16 * i + r) * C_;
#pragma unroll
      for (int j = 0; j < 4; ++j) {
        const int c = n0 + wc * 64 + j * 16 + (lane & 15);
        const float val = acc[i][j][r] * scl[j] + sft[j];
        if (job.out32) job.out32[mrow + c] = val;
        else           job.out16[mrow + c] = f2bf(val);
      }
    }
  }
}

// ---------------------------------------------------------------------------
// LIF (T-sequential, hard threshold >= 1, reset to 0) for q,k + transposes:
//   qs [t,b,n,c] bf16 spikes; ktr,vtr [t,b,c,n] bf16.
// ---------------------------------------------------------------------------
__global__ __launch_bounds__(256) void lif_transpose(
    const float* __restrict__ yq, const float* __restrict__ yk,
    const unsigned short* __restrict__ yv,
    unsigned short* __restrict__ qs, unsigned short* __restrict__ ktr,
    unsigned short* __restrict__ vtr) {
  const int c0 = blockIdx.x * 64, n0 = blockIdx.y * 64, b = blockIdx.z;
  const int tid = threadIdx.x;
  const int cl = tid & 63;
  const int nr = tid >> 6;

  __shared__ unsigned short tile[64][65];

  float vq[16], vk[16];
#pragma unroll
  for (int i = 0; i < 16; ++i) { vq[i] = 0.f; vk[i] = 0.f; }

  for (int t = 0; t < T_; ++t) {
    const size_t base  = (((size_t)t * B_ + b) * N_ + n0) * C_ + c0;
    const size_t tbase = (((size_t)t * B_ + b) * C_ + c0) * N_ + n0;
#pragma unroll
    for (int i = 0; i < 16; ++i) {
      const size_t off = base + (size_t)(nr + 4 * i) * C_ + cl;
      const float y = yq[off];
      vq[i] += (y - vq[i]) * 0.5f;
      const bool sp = vq[i] >= 1.0f;
      qs[off] = sp ? (unsigned short)0x3F80 : (unsigned short)0;
      if (sp) vq[i] = 0.f;
    }
#pragma unroll
    for (int i = 0; i < 16; ++i) {
      const float y = yk[base + (size_t)(nr + 4 * i) * C_ + cl];
      vk[i] += (y - vk[i]) * 0.5f;
      const bool sp = vk[i] >= 1.0f;
      tile[nr + 4 * i][cl] = sp ? (unsigned short)0x3F80 : (unsigned short)0;
      if (sp) vk[i] = 0.f;
    }
    __syncthreads();
#pragma unroll
    for (int i = 0; i < 16; ++i)
      ktr[tbase + (size_t)(nr + 4 * i) * N_ + cl] = tile[cl][nr + 4 * i];
    __syncthreads();
#pragma unroll
    for (int i = 0; i < 16; ++i)
      tile[nr + 4 * i][cl] = yv[base + (size_t)(nr + 4 * i) * C_ + cl];
    __syncthreads();
#pragma unroll
    for (int i = 0; i < 16; ++i)
      vtr[tbase + (size_t)(nr + 4 * i) * N_ + cl] = tile[cl][nr + 4 * i];
    __syncthreads();
  }
}

// ---------------------------------------------------------------------------
// KV[d,e] = sum_m K[m,d] V[m,e] per (t,b,h) from transposed [t,b,c,n] layout.
// 256 blocks = (head, m-half); per-wave f32 partials (deterministic).
// ---------------------------------------------------------------------------
__global__ __launch_bounds__(256) void kv_gemm(const unsigned short* __restrict__ ktr,
                                               const unsigned short* __restrict__ vtr,
                                               float* __restrict__ kvp) {
  const int bid = blockIdx.x;
  const int head = bid >> 1;
  const int mh = bid & 1;
  const int tb = head >> 3;
  const int h = head & 7;
  const int wv = threadIdx.x >> 6, lane = threadIdx.x & 63;
  const int m0 = mh * 512 + wv * 128;
  const size_t cbase = (size_t)tb * C_ + h * 64;
  const int rsel = lane & 15, koff = (lane >> 4) * 8;

  floatx4 acc[4][4];
#pragma unroll
  for (int i = 0; i < 4; ++i)
#pragma unroll
    for (int j = 0; j < 4; ++j) acc[i][j] = floatx4{0.f, 0.f, 0.f, 0.f};

#pragma unroll
  for (int s = 0; s < 4; ++s) {
    const int m = m0 + s * 32 + koff;
    bf16x8 a[4], b[4];
#pragma unroll
    for (int dt = 0; dt < 4; ++dt)
      a[dt] = *(const bf16x8*)(ktr + (cbase + dt * 16 + rsel) * N_ + m);
#pragma unroll
    for (int et = 0; et < 4; ++et)
      b[et] = *(const bf16x8*)(vtr + (cbase + et * 16 + rsel) * N_ + m);
#pragma unroll
    for (int dt = 0; dt < 4; ++dt)
#pragma unroll
      for (int et = 0; et < 4; ++et)
        acc[dt][et] = __builtin_amdgcn_mfma_f32_16x16x32_bf16(a[dt], b[et], acc[dt][et], 0, 0, 0);
  }

  float* outp = kvp + ((size_t)head * 8 + mh * 4 + wv) * 4096;
  const int dbase = (lane >> 4) * 4;
  const int e0 = lane & 15;
#pragma unroll
  for (int dt = 0; dt < 4; ++dt)
#pragma unroll
    for (int et = 0; et < 4; ++et)
#pragma unroll
      for (int r = 0; r < 4; ++r)
        outp[(dt * 16 + dbase + r) * 64 + et * 16 + e0] = acc[dt][et][r];
}

// Reduce 8 partials, scale 0.125, emit bf16 KVT[head][e][d].
__global__ __launch_bounds__(256) void kv_reduce(const float* __restrict__ kvp,
                                                 unsigned short* __restrict__ kvt) {
  const int gid = blockIdx.x * 256 + threadIdx.x;
  const int idx4 = gid * 4;
  const int head = idx4 >> 12;
  const int rem = idx4 & 4095;
  const int e = rem >> 6, d0 = rem & 63;
  const float* p = kvp + (size_t)head * 8 * 4096;
  unsigned short rr[4];
#pragma unroll
  for (int j = 0; j < 4; ++j) {
    float s = 0.f;
#pragma unroll
    for (int pp = 0; pp < 8; ++pp) s += p[pp * 4096 + (d0 + j) * 64 + e];
    rr[j] = f2bf(0.125f * s);
  }
  uint2 o;
  o.x = (unsigned)rr[0] | ((unsigned)rr[1] << 16);
  o.y = (unsigned)rr[2] | ((unsigned)rr[3] << 16);
  *(uint2*)(kvt + idx4) = o;
}

// O[n, h*64+e] = sum_d Q[n, h*64+d] * KVT[h][e][d]
__global__ __launch_bounds__(256) void av_gemm(const unsigned short* __restrict__ qs,
                                               const unsigned short* __restrict__ kvt,
                                               unsigned short* __restrict__ obuf) {
  const int bx = blockIdx.x;
  const int tb = bx >> 3, nt = bx & 7;
  const int wv = threadIdx.x >> 6, lane = threadIdx.x & 63;
  const int n0 = nt * 128 + wv * 32;
  const int rsel = lane & 15, koff = (lane >> 4) * 8;
  const size_t qbase = ((size_t)tb * N_ + n0) * C_;

#pragma unroll 1
  for (int h = 0; h < H_; ++h) {
    floatx4 acc[2][4];
#pragma unroll
    for (int i = 0; i < 2; ++i)
#pragma unroll
      for (int j = 0; j < 4; ++j) acc[i][j] = floatx4{0.f, 0.f, 0.f, 0.f};
    const unsigned short* kvh = kvt + ((size_t)tb * 8 + h) * 4096;
#pragma unroll
    for (int s = 0; s < 2; ++s) {
      bf16x8 a[2], b[4];
#pragma unroll
      for (int i = 0; i < 2; ++i)
        a[i] = *(const bf16x8*)(qs + qbase + (size_t)(i * 16 + rsel) * C_ + h * 64 + s * 32 + koff);
#pragma unroll
      for (int et = 0; et < 4; ++et)
        b[et] = *(const bf16x8*)(kvh + (et * 16 + rsel) * 64 + s * 32 + koff);
#pragma unroll
      for (int i = 0; i < 2; ++i)
#pragma unroll
        for (int et = 0; et < 4; ++et)
          acc[i][et] = __builtin_amdgcn_mfma_f32_16x16x32_bf16(a[i], b[et], acc[i][et], 0, 0, 0);
    }
#pragma unroll
    for (int i = 0; i < 2; ++i)
#pragma unroll
      for (int et = 0; et < 4; ++et)
#pragma unroll
        for (int r = 0; r < 4; ++r) {
          const int n = n0 + i * 16 + (lane >> 4) * 4 + r;
          obuf[((size_t)tb * N_ + n) * C_ + h * 64 + et * 16 + rsel] = f2bf(acc[i][et][r]);
        }
  }
}

// ---------------------------------------------------------------------------
extern "C" void kernel_launch(void* const* d_in, const int* in_sizes, int n_in,
                              void* d_out, int out_size, void* d_ws, size_t ws_size,
                              hipStream_t stream) {
  const float* x  = (const float*)d_in[0];
  const float* qw = (const float*)d_in[2];
  const float* qb = (const float*)d_in[3];
  const float* qg = (const float*)d_in[4];
  const float* qbt= (const float*)d_in[5];
  const float* qm = (const float*)d_in[6];
  const float* qv = (const float*)d_in[7];
  const float* kw = (const float*)d_in[8];
  const float* kb = (const float*)d_in[9];
  const float* kg = (const float*)d_in[10];
  const float* kbt= (const float*)d_in[11];
  const float* km = (const float*)d_in[12];
  const float* kvv= (const float*)d_in[13];
  const float* vw = (const float*)d_in[14];
  const float* vb = (const float*)d_in[15];
  const float* vg = (const float*)d_in[16];
  const float* vbt= (const float*)d_in[17];
  const float* vm = (const float*)d_in[18];
  const float* vvv= (const float*)d_in[19];
  const float* pw = (const float*)d_in[20];
  const float* pb = (const float*)d_in[21];
  const float* pg = (const float*)d_in[22];
  const float* pbt= (const float*)d_in[23];
  const float* pm = (const float*)d_in[24];
  const float* pv = (const float*)d_in[25];

  char* ws = (char*)d_ws;
  unsigned short* X3  = (unsigned short*)(ws + 0);            // 48 MB [16384][1536]
  unsigned short* W3q = (unsigned short*)(ws + 50331648ull);  // 1.5 MB
  unsigned short* W3k = (unsigned short*)(ws + 51904512ull);  // 1.5 MB
  unsigned short* Wvb = (unsigned short*)(ws + 53477376ull);  // 0.5 MB
  float*          yq  = (float*)(ws + 54001664ull);           // 32 MB
  float*          yk  = (float*)(ws + 87556096ull);           // 32 MB
  unsigned short* yv  = (unsigned short*)(ws + 121110528ull); // 16 MB
  unsigned short* Wpb = (unsigned short*)(ws + 137887744ull); // 0.5 MB (live to end)
  // after QKV gemm: X3/W3 dead -> spike buffers
  unsigned short* qsb = (unsigned short*)(ws + 0);            // 16 MB
  unsigned short* ktb = (unsigned short*)(ws + 16777216ull);  // 16 MB
  unsigned short* vtb = (unsigned short*)(ws + 33554432ull);  // 16 MB
  // after lif: yq/yk dead -> attention scratch
  float*          kvp = (float*)(ws + 54001664ull);           // 16 MB
  unsigned short* kvt = (unsigned short*)(ws + 70778880ull);  // 1 MB
  unsigned short* ob  = (unsigned short*)(ws + 71827456ull);  // 16 MB

  prep_split<<<dim3(M_ * C_ / 4 / 256), 256, 0, stream>>>(x, X3, M_ * C_, 0);
  prep_split<<<dim3(C_ * C_ / 4 / 256), 256, 0, stream>>>(qw, W3q, C_ * C_, 1);
  prep_split<<<dim3(C_ * C_ / 4 / 256), 256, 0, stream>>>(kw, W3k, C_ * C_, 1);
  prep_cast<<<dim3(C_ * C_ / 4 / 256), 256, 0, stream>>>(vw, Wvb, C_ * C_);
  prep_cast<<<dim3(C_ * C_ / 4 / 256), 256, 0, stream>>>(pw, Wpb, C_ * C_);

  GemmJobs jq;
  jq.j[0] = GemmJob{W3q, 1536, 1536, qb, qg, qbt, qm, qv,  yq, nullptr};
  jq.j[1] = GemmJob{W3k, 1536, 1536, kb, kg, kbt, km, kvv, yk, nullptr};
  jq.j[2] = GemmJob{Wvb, 512,  512,  vb, vg, vbt, vm, vvv, nullptr, yv};
  gemm_bn<<<dim3(M_ / 128 * 4 * 3), 256, 0, stream>>>(X3, 1536, jq, 3);

  lif_transpose<<<dim3(C_ / 64, N_ / 64, B_), 256, 0, stream>>>(yq, yk, yv, qsb, ktb, vtb);

  kv_gemm<<<dim3(256), 256, 0, stream>>>(ktb, vtb, kvp);
  kv_reduce<<<dim3(512), 256, 0, stream>>>(kvp, kvt);
  av_gemm<<<dim3(128), 256, 0, stream>>>(qsb, kvt, ob);

  GemmJobs jp;
  jp.j[0] = GemmJob{Wpb, 512, 512, pb, pg, pbt, pm, pv, (float*)d_out, nullptr};
  jp.j[1] = jp.j[0];
  jp.j[2] = jp.j[0];
  gemm_bn<<<dim3(M_ / 128 * 4), 256, 0, stream>>>(ob, 512, jp, 1);
}